// Round 12
// baseline (94.216 us; speedup 1.0000x reference)
//
#include <hip/hip_runtime.h>
#include <hip/hip_bf16.h>

#define B_DIM 64
#define H_DIM 256
#define NCHG 4            // t-groups (grid y) -> 256 blocks = 1/CU
#define CHUNKS 8          // chunks per block
#define TCH 64            // t-rows per chunk

typedef __attribute__((ext_vector_type(8))) short short8;
typedef __attribute__((ext_vector_type(4))) float f32x4;

__device__ __forceinline__ unsigned short bfbits(float f) {
    __hip_bfloat16 h = __float2bfloat16(f);
    unsigned short u;
    __builtin_memcpy(&u, &h, 2);
    return u;
}
__device__ __forceinline__ float fexp(float x) {
    float r;
    asm("v_exp_f32 %0, %1" : "=v"(r) : "v"(x * 1.4426950408889634f));
    return r;
}
__device__ __forceinline__ float ftanh(float x) {
    float e, r;
    asm("v_exp_f32 %0, %1" : "=v"(e) : "v"(x * 2.8853900817779268f));
    asm("v_rcp_f32 %0, %1" : "=v"(r) : "v"(e + 1.0f));
    return 1.0f - 2.0f * r;
}
__device__ __forceinline__ float fast_sigmoid(float x) {
    return 1.0f / (1.0f + __expf(-x));
}
// raw barrier: LDS visibility only — in-flight global loads survive (no vmcnt drain)
__device__ __forceinline__ void lds_barrier() {
    asm volatile("s_waitcnt lgkmcnt(0)" ::: "memory");
    __builtin_amdgcn_s_barrier();
    __builtin_amdgcn_sched_barrier(0);
}

// K0: fused WmT prep (blocks 0..255) + qs GEMV (blocks 256..319)
__global__ void prep_qs_kernel(const float* __restrict__ W_a1,
                               const float* __restrict__ input,
                               const float* __restrict__ state,
                               unsigned short* __restrict__ WmT,
                               float* __restrict__ qs) {
    __shared__ float cat[512];
    int bid = blockIdx.x, tid = threadIdx.x;
    if (bid < 256) {
        WmT[tid * 256 + bid] = bfbits(W_a1[(512 + bid) * 256 + tid]);
    } else {
        int b = bid - 256;
        cat[tid] = input[b * 256 + tid];
        cat[256 + tid] = state[b * 256 + tid];
        __syncthreads();
        int a = tid;
        float s0 = 0.f, s1 = 0.f, s2 = 0.f, s3 = 0.f;
        #pragma unroll 4
        for (int k = 0; k < 512; k += 4) {
            s0 += cat[k]     * W_a1[(k)     * 256 + a];
            s1 += cat[k + 1] * W_a1[(k + 1) * 256 + a];
            s2 += cat[k + 2] * W_a1[(k + 2) * 256 + a];
            s3 += cat[k + 3] * W_a1[(k + 3) * 256 + a];
        }
        qs[b * 256 + a] = (s0 + s1) + (s2 + s3);
    }
}

// K1: R11 datapath + raw barriers (no vmcnt drain) + 2-deep reg prefetch.
// grid (64, 4) = 256 blocks = 1/CU; 512 threads; LDS 69.6 KB; VGPR ~148 ok.
__global__ __launch_bounds__(512, 1) void attn_kernel(
    const float* __restrict__ memory, const int* __restrict__ mask,
    const unsigned short* __restrict__ WmT,
    const float* __restrict__ qs, const float* __restrict__ w_a2,
    float* __restrict__ part_l, float* __restrict__ part_acc)
{
    extern __shared__ char smem[];
    unsigned short* slab0 = (unsigned short*)smem;            // [64][256] bf16, swizzled
    unsigned short* slab1 = (unsigned short*)(smem + 32768);
    float* lpart = (float*)(smem + 65536);                    // [8][64]
    int*   maskL = (int*)(smem + 65536 + 2048);               // [512]

    int b = blockIdx.x, g = blockIdx.y;
    int tid = threadIdx.x;
    int lane = tid & 63, w = tid >> 6;
    int lr = lane & 15, lh = lane >> 4;
    int tbase = g * (CHUNKS * TCH);
    const float* mbase = memory + (size_t)tbase * (B_DIM * H_DIM) + b * H_DIM;

    // ---- one-time preloads ----
    int wa0 = w * 32;
    short8 areg[8][2];                            // 64 persistent VGPRs
    #pragma unroll
    for (int kk = 0; kk < 8; ++kk)
        #pragma unroll
        for (int mf = 0; mf < 2; ++mf)
            areg[kk][mf] = *(const short8*)(WmT + (wa0 + mf * 16 + lr) * 256 + kk * 32 + lh * 8);

    float qv[2][4], wv[2][4];
    #pragma unroll
    for (int mf = 0; mf < 2; ++mf)
        #pragma unroll
        for (int r = 0; r < 4; ++r) {
            int a = wa0 + mf * 16 + lh * 4 + r;
            qv[mf][r] = qs[b * 256 + a];
            wv[mf][r] = w_a2[a];
        }

    maskL[tid] = mask[(tbase + tid) * B_DIM + b];

    int wby = (lane * 8) ^ (w << 4);              // swizzled byte off (row&7 == w)

    float4 ldA[8], ldB[8];
#define ISSUE(dst, q)                                                          \
    _Pragma("unroll") for (int i = 0; i < 8; ++i)                              \
        dst[i] = *((const float4*)(mbase + (size_t)((q) * TCH + i * 8 + w) *   \
                                   (B_DIM * H_DIM)) + lane);
#define WRITE(src, sl)                                                         \
    _Pragma("unroll") for (int i = 0; i < 8; ++i) {                            \
        ushort4 o;                                                             \
        o.x = bfbits(src[i].x); o.y = bfbits(src[i].y);                        \
        o.z = bfbits(src[i].z); o.w = bfbits(src[i].w);                        \
        *(ushort4*)((char*)(sl) + (i * 8 + w) * 512 + wby) = o;                \
    }

    // prologue: chunk 0 -> slab0; issue chunk 1 into ldB
    ISSUE(ldA, 0)
    WRITE(ldA, slab0)
    ISSUE(ldB, 1)
    lds_barrier();

    float a8[8] = {0.f, 0.f, 0.f, 0.f, 0.f, 0.f, 0.f, 0.f};
    float l_acc = 0.f;
    int slice4 = ((lane >> 5) + 2 * w) * 4;       // PV t-base
    int hpvb = (lane & 31) * 16;                  // PV h byte-base

    #pragma unroll
    for (int s = 0; s < CHUNKS; ++s) {
        char* curp = (char*)((s & 1) ? slab1 : slab0);
        char* nxtp = (char*)((s & 1) ? slab0 : slab1);
        const char* cur = curp;

        // a. issue loads for chunk s+2 into R[s&1] (2-deep; survives barriers)
        if (s + 2 < CHUNKS) {
            if ((s & 1) == 0) { ISSUE(ldA, s + 2) }
            else              { ISSUE(ldB, s + 2) }
        }

        // b. MFMA(s): C[a][t], A persistent regs, B from LDS
        f32x4 acc[2][4];
        #pragma unroll
        for (int mf = 0; mf < 2; ++mf)
            #pragma unroll
            for (int nf = 0; nf < 4; ++nf)
                acc[mf][nf] = (f32x4){0.f, 0.f, 0.f, 0.f};
        #pragma unroll
        for (int kk = 0; kk < 8; ++kk) {
            int kbyte = kk * 64 + lh * 16;
            #pragma unroll
            for (int nf = 0; nf < 4; ++nf) {
                int t = nf * 16 + lr;
                int sw = kbyte ^ ((t & 7) << 4);
                short8 bfr = *(const short8*)(cur + t * 512 + sw);
                acc[0][nf] = __builtin_amdgcn_mfma_f32_16x16x32_bf16(areg[kk][0], bfr, acc[0][nf], 0, 0, 0);
                acc[1][nf] = __builtin_amdgcn_mfma_f32_16x16x32_bf16(areg[kk][1], bfr, acc[1][nf], 0, 0, 0);
            }
        }

        // c. write chunk s+1 (loaded last iter) into idle slab
        if (s + 1 < CHUNKS) {
            if ((s & 1) == 0) { WRITE(ldB, nxtp) }   // R[(s+1)&1] = ldB when s even
            else              { WRITE(ldA, nxtp) }
        }

        // d. epilogue: reduce over a (8 tanh + 2 shuffles)
        #pragma unroll
        for (int nf = 0; nf < 4; ++nf) {
            float sv = 0.f;
            #pragma unroll
            for (int mf = 0; mf < 2; ++mf)
                #pragma unroll
                for (int r = 0; r < 4; ++r)
                    sv += wv[mf][r] * ftanh(qv[mf][r] + acc[mf][nf][r]);
            sv += __shfl_xor(sv, 16);
            sv += __shfl_xor(sv, 32);
            if (lh == 0) lpart[w * 64 + nf * 16 + lr] = sv;
        }
        lds_barrier();                            // A: lpart + slab writes visible

        // e. p = exp(logit), no max-tracking (|logit| <= ~13, f32-safe)
        float lg = 0.f;
        #pragma unroll
        for (int ww = 0; ww < 8; ++ww) lg += lpart[ww * 64 + lane];
        float pself = maskL[s * 64 + lane] ? fexp(lg) : 0.f;
        if (w == 0) l_acc += pself;

        // f. PV from slab[cur]; p via in-wave shuffle
        #pragma unroll
        for (int tt = 0; tt < 4; ++tt) {
            int tl = slice4 + tt;
            float pt = __shfl(pself, tl);         // tl in [8w, 8w+8) -> same wave
            int swb = hpvb ^ ((tl & 7) << 4);
            uint4 u = *(const uint4*)(cur + tl * 512 + swb);
            a8[0] += pt * __uint_as_float(u.x << 16);
            a8[1] += pt * __uint_as_float(u.x & 0xFFFF0000u);
            a8[2] += pt * __uint_as_float(u.y << 16);
            a8[3] += pt * __uint_as_float(u.y & 0xFFFF0000u);
            a8[4] += pt * __uint_as_float(u.z << 16);
            a8[5] += pt * __uint_as_float(u.z & 0xFFFF0000u);
            a8[6] += pt * __uint_as_float(u.w << 16);
            a8[7] += pt * __uint_as_float(u.w & 0xFFFF0000u);
        }
        lds_barrier();                            // B: PV done -> cur free for restage
    }
#undef ISSUE
#undef WRITE

    // ---- final combine: alias acc2 over slab0 (dead) ----
    __syncthreads();
    float* acc2 = (float*)smem;                   // [16][256]
    int oct = lane & 31, slice = 2 * w + (lane >> 5), h0 = oct * 8;
    *(float4*)(&acc2[slice * 256 + h0])     = (float4){a8[0], a8[1], a8[2], a8[3]};
    *(float4*)(&acc2[slice * 256 + h0 + 4]) = (float4){a8[4], a8[5], a8[6], a8[7]};
    __syncthreads();
    int pidx = g * B_DIM + b;
    if (tid < 256) {
        float ssum = 0.f;
        #pragma unroll
        for (int sl = 0; sl < 16; ++sl) ssum += acc2[sl * 256 + tid];
        part_acc[(size_t)pidx * 256 + tid] = ssum;
    }
    if (w == 0) {
        #pragma unroll
        for (int d = 1; d < 64; d <<= 1) l_acc += __shfl_xor(l_acc, d);
        if (lane == 0) part_l[pidx] = l_acc;
    }
}

// K2: fused merge (plain sums over 4 groups) + gate GEMV. block = one b.
__global__ void mergegate_kernel(const float* __restrict__ part_l,
                                 const float* __restrict__ part_acc,
                                 const float* __restrict__ input,
                                 const float* __restrict__ W_gate,
                                 float* __restrict__ gated) {
    __shared__ float ni[512];
    int b = blockIdx.x, tid = threadIdx.x;
    if (tid >= 256) {
        int k = tid - 256;
        ni[k] = input[b * 256 + k];
    } else {
        int h = tid;
        float L = 0.f, s = 0.f;
        #pragma unroll
        for (int c = 0; c < NCHG; ++c) {
            L += part_l[c * 64 + b];
            s += part_acc[(size_t)(c * 64 + b) * 256 + h];
        }
        ni[256 + h] = s / L;
    }
    __syncthreads();
    int j = tid;
    float s0 = 0.f, s1 = 0.f, s2 = 0.f, s3 = 0.f;
    #pragma unroll 4
    for (int k = 0; k < 512; k += 4) {
        s0 += ni[k]     * W_gate[(k)     * 512 + j];
        s1 += ni[k + 1] * W_gate[(k + 1) * 512 + j];
        s2 += ni[k + 2] * W_gate[(k + 2) * 512 + j];
        s3 += ni[k + 3] * W_gate[(k + 3) * 512 + j];
    }
    float s = (s0 + s1) + (s2 + s3);
    gated[b * 512 + j] = ni[j] * fast_sigmoid(s);
}

// K3: GRU cell. grid 256 = (16 b-tiles x 16 h-tiles), block 768.
__global__ __launch_bounds__(768) void gru_kernel(
    const float* __restrict__ gated, const float* __restrict__ state,
    const float* __restrict__ W_ih, const float* __restrict__ W_hh,
    const float* __restrict__ b_ih, const float* __restrict__ b_hh,
    float* __restrict__ out) {
    __shared__ float ld_g[4][512];
    __shared__ float ld_s[4][256];
    __shared__ float xi[3][16][4];
    __shared__ float xh[3][16][4];
    int ht = blockIdx.x & 15, bt = blockIdx.x >> 4;
    int tid = threadIdx.x;
    #pragma unroll
    for (int i = 0; i < 3; ++i) {
        int idx = i * 768 + tid;
        if (idx < 2048) ld_g[idx >> 9][idx & 511] = gated[(bt * 4 + (idx >> 9)) * 512 + (idx & 511)];
    }
    #pragma unroll
    for (int i = 0; i < 2; ++i) {
        int idx = i * 768 + tid;
        if (idx < 1024) ld_s[idx >> 8][idx & 255] = state[(bt * 4 + (idx >> 8)) * 256 + (idx & 255)];
    }

    int gid = tid >> 4, lk = tid & 15;
    int gate = gid >> 4, hl = gid & 15;
    int j = gate * 256 + ht * 16 + hl;

    float4 wi[8], wh[4];
    #pragma unroll
    for (int it = 0; it < 8; ++it)
        wi[it] = *(const float4*)(W_ih + (size_t)j * 512 + it * 64 + lk * 4);
    #pragma unroll
    for (int it = 0; it < 4; ++it)
        wh[it] = *(const float4*)(W_hh + (size_t)j * 256 + it * 64 + lk * 4);
    float bi = b_ih[j], bh = b_hh[j];
    __syncthreads();

    #pragma unroll
    for (int bb = 0; bb < 4; ++bb) {
        float g0 = 0.f, g1 = 0.f;
        #pragma unroll
        for (int it = 0; it < 8; ++it) {
            float4 gv = *(const float4*)(&ld_g[bb][it * 64 + lk * 4]);
            g0 += wi[it].x * gv.x + wi[it].z * gv.z;
            g1 += wi[it].y * gv.y + wi[it].w * gv.w;
        }
        float h0 = 0.f, h1 = 0.f;
        #pragma unroll
        for (int it = 0; it < 4; ++it) {
            float4 sv = *(const float4*)(&ld_s[bb][it * 64 + lk * 4]);
            h0 += wh[it].x * sv.x + wh[it].z * sv.z;
            h1 += wh[it].y * sv.y + wh[it].w * sv.w;
        }
        float gi_ = g0 + g1, gh_ = h0 + h1;
        #pragma unroll
        for (int m = 1; m < 16; m <<= 1) {
            gi_ += __shfl_xor(gi_, m);
            gh_ += __shfl_xor(gh_, m);
        }
        if (lk == 0) { xi[gate][hl][bb] = gi_ + bi; xh[gate][hl][bb] = gh_ + bh; }
    }
    __syncthreads();
    if (tid < 64) {
        int bb = tid >> 4, hl2 = tid & 15;
        float ir = xi[0][hl2][bb], hr = xh[0][hl2][bb];
        float iz = xi[1][hl2][bb], hz = xh[1][hl2][bb];
        float in_ = xi[2][hl2][bb], hn = xh[2][hl2][bb];
        float r = fast_sigmoid(ir + hr);
        float z = fast_sigmoid(iz + hz);
        float n = 1.0f - 2.0f / (__expf(2.0f * (in_ + r * hn)) + 1.0f);
        out[(bt * 4 + bb) * 256 + ht * 16 + hl2] =
            (1.f - z) * n + z * ld_s[bb][ht * 16 + hl2];
    }
}

extern "C" void kernel_launch(void* const* d_in, const int* in_sizes, int n_in,
                              void* d_out, int out_size, void* d_ws, size_t ws_size,
                              hipStream_t stream) {
    const float* input  = (const float*)d_in[0];
    const float* memory = (const float*)d_in[1];
    const int*   mask   = (const int*)d_in[2];
    const float* state  = (const float*)d_in[3];
    const float* W_a1   = (const float*)d_in[4];
    const float* w_a2   = (const float*)d_in[5];
    const float* W_gate = (const float*)d_in[6];
    const float* W_ih   = (const float*)d_in[7];
    const float* W_hh   = (const float*)d_in[8];
    const float* b_ih   = (const float*)d_in[9];
    const float* b_hh   = (const float*)d_in[10];
    float* out = (float*)d_out;

    char* ws = (char*)d_ws;
    unsigned short* WmT = (unsigned short*)(ws + 0);        // 131072 B
    float* qs       = (float*)(ws + 131072);                // 65536 B
    float* gated    = (float*)(ws + 196608);                // 131072 B
    float* part_l   = (float*)(ws + 327680);                // 1024 B   [g][b]
    float* part_acc = (float*)(ws + 335872);                // 262144 B [g][b][h]

    prep_qs_kernel<<<320, 256, 0, stream>>>(W_a1, input, state, WmT, qs);

    (void)hipFuncSetAttribute((const void*)attn_kernel,
                              hipFuncAttributeMaxDynamicSharedMemorySize, 69632);
    attn_kernel<<<dim3(B_DIM, NCHG), 512, 69632, stream>>>(
        memory, mask, WmT, qs, w_a2, part_l, part_acc);

    mergegate_kernel<<<64, 512, 0, stream>>>(part_l, part_acc, input, W_gate, gated);
    gru_kernel<<<256, 768, 0, stream>>>(gated, state, W_ih, W_hh, b_ih, b_hh, out);
}

// Round 13
// 78.603 us; speedup vs baseline: 1.1986x; 1.1986x over previous
//
#include <hip/hip_runtime.h>
#include <hip/hip_bf16.h>

#define B_DIM 64
#define H_DIM 256
#define NCHG 8            // t-groups (grid y) -> 512 blocks = 2/CU
#define CHUNKS 4          // chunks per block
#define TCH 64            // t-rows per chunk

typedef __attribute__((ext_vector_type(8))) short short8;
typedef __attribute__((ext_vector_type(4))) float f32x4;

__device__ __forceinline__ unsigned short bfbits(float f) {
    __hip_bfloat16 h = __float2bfloat16(f);
    unsigned short u;
    __builtin_memcpy(&u, &h, 2);
    return u;
}
__device__ __forceinline__ float fexp(float x) {
    float r;
    asm("v_exp_f32 %0, %1" : "=v"(r) : "v"(x * 1.4426950408889634f));
    return r;
}
__device__ __forceinline__ float ftanh(float x) {
    float e, r;
    asm("v_exp_f32 %0, %1" : "=v"(e) : "v"(x * 2.8853900817779268f));
    asm("v_rcp_f32 %0, %1" : "=v"(r) : "v"(e + 1.0f));
    return 1.0f - 2.0f * r;
}
__device__ __forceinline__ float fsigmoid(float x) {
    float e, r;
    asm("v_exp_f32 %0, %1" : "=v"(e) : "v"(x * -1.4426950408889634f));
    asm("v_rcp_f32 %0, %1" : "=v"(r) : "v"(e + 1.0f));
    return r;
}
// raw barrier: LDS visibility only — in-flight global loads survive (no vmcnt drain)
__device__ __forceinline__ void lds_barrier() {
    asm volatile("s_waitcnt lgkmcnt(0)" ::: "memory");
    __builtin_amdgcn_s_barrier();
    __builtin_amdgcn_sched_barrier(0);
}

// K0: fused WmT prep (blocks 0..255) + qs GEMV (blocks 256..319)
__global__ void prep_qs_kernel(const float* __restrict__ W_a1,
                               const float* __restrict__ input,
                               const float* __restrict__ state,
                               unsigned short* __restrict__ WmT,
                               float* __restrict__ qs) {
    __shared__ float cat[512];
    int bid = blockIdx.x, tid = threadIdx.x;
    if (bid < 256) {
        WmT[tid * 256 + bid] = bfbits(W_a1[(512 + bid) * 256 + tid]);
    } else {
        int b = bid - 256;
        cat[tid] = input[b * 256 + tid];
        cat[256 + tid] = state[b * 256 + tid];
        __syncthreads();
        int a = tid;
        float s0 = 0.f, s1 = 0.f, s2 = 0.f, s3 = 0.f;
        #pragma unroll 4
        for (int k = 0; k < 512; k += 4) {
            s0 += cat[k]     * W_a1[(k)     * 256 + a];
            s1 += cat[k + 1] * W_a1[(k + 1) * 256 + a];
            s2 += cat[k + 2] * W_a1[(k + 2) * 256 + a];
            s3 += cat[k + 3] * W_a1[(k + 3) * 256 + a];
        }
        qs[b * 256 + a] = (s0 + s1) + (s2 + s3);
    }
}

// K1: R11 datapath; write-late staging (end of iter) + raw barriers so the
// single ld[8] prefetch spans the whole chunk (~2K cyc window), no vmcnt
// drains, no extra registers. grid (64, 8) = 512 blocks = 2/CU. VGPR ~116.
__global__ __launch_bounds__(512, 2) void attn_kernel(
    const float* __restrict__ memory, const int* __restrict__ mask,
    const unsigned short* __restrict__ WmT,
    const float* __restrict__ qs, const float* __restrict__ w_a2,
    float* __restrict__ part_l, float* __restrict__ part_acc)
{
    extern __shared__ char smem[];
    unsigned short* slab0 = (unsigned short*)smem;            // [64][256] bf16, swizzled
    unsigned short* slab1 = (unsigned short*)(smem + 32768);
    float* lpart = (float*)(smem + 65536);                    // [8][64]
    int*   maskL = (int*)(smem + 65536 + 2048);               // [256]

    int b = blockIdx.x, g = blockIdx.y;
    int tid = threadIdx.x;
    int lane = tid & 63, w = tid >> 6;
    int lr = lane & 15, lh = lane >> 4;
    int tbase = g * (CHUNKS * TCH);
    const float* mbase = memory + (size_t)tbase * (B_DIM * H_DIM) + b * H_DIM;

    // ---- one-time preloads ----
    int wa0 = w * 32;
    short8 areg[8][2];                            // 64 persistent VGPRs
    #pragma unroll
    for (int kk = 0; kk < 8; ++kk)
        #pragma unroll
        for (int mf = 0; mf < 2; ++mf)
            areg[kk][mf] = *(const short8*)(WmT + (wa0 + mf * 16 + lr) * 256 + kk * 32 + lh * 8);

    float qv[2][4], wv[2][4];
    #pragma unroll
    for (int mf = 0; mf < 2; ++mf)
        #pragma unroll
        for (int r = 0; r < 4; ++r) {
            int a = wa0 + mf * 16 + lh * 4 + r;
            qv[mf][r] = qs[b * 256 + a];
            wv[mf][r] = w_a2[a];
        }

    if (tid < CHUNKS * TCH) maskL[tid] = mask[(tbase + tid) * B_DIM + b];

    int wby = (lane * 8) ^ (w << 4);              // swizzled byte off (row&7 == w)

    float4 ld[8];
#define ISSUE(q)                                                               \
    _Pragma("unroll") for (int i = 0; i < 8; ++i)                              \
        ld[i] = *((const float4*)(mbase + (size_t)((q) * TCH + i * 8 + w) *    \
                                  (B_DIM * H_DIM)) + lane);
#define WRITE(sl)                                                              \
    _Pragma("unroll") for (int i = 0; i < 8; ++i) {                            \
        ushort4 o;                                                             \
        o.x = bfbits(ld[i].x); o.y = bfbits(ld[i].y);                          \
        o.z = bfbits(ld[i].z); o.w = bfbits(ld[i].w);                          \
        *(ushort4*)((char*)(sl) + (i * 8 + w) * 512 + wby) = o;                \
    }

    // prologue: chunk 0 -> slab0
    ISSUE(0)
    WRITE(slab0)

    float a8[8] = {0.f, 0.f, 0.f, 0.f, 0.f, 0.f, 0.f, 0.f};
    float l_acc = 0.f;
    int slice4 = ((lane >> 5) + 2 * w) * 4;       // PV t-base
    int hpvb = (lane & 31) * 16;                  // PV h byte-base

    for (int s = 0; s < CHUNKS; ++s) {
        const char* cur = (const char*)((s & 1) ? slab1 : slab0);
        char* nxt = (char*)((s & 1) ? slab0 : slab1);

        lds_barrier();                            // top: slab writes visible

        // a. issue loads for chunk s+1 — in flight across the WHOLE iteration
        if (s + 1 < CHUNKS) { ISSUE(s + 1) }

        // b. MFMA(s): C[a][t], A persistent regs, B from LDS
        f32x4 acc[2][4];
        #pragma unroll
        for (int mf = 0; mf < 2; ++mf)
            #pragma unroll
            for (int nf = 0; nf < 4; ++nf)
                acc[mf][nf] = (f32x4){0.f, 0.f, 0.f, 0.f};
        #pragma unroll
        for (int kk = 0; kk < 8; ++kk) {
            int kbyte = kk * 64 + lh * 16;
            #pragma unroll
            for (int nf = 0; nf < 4; ++nf) {
                int t = nf * 16 + lr;
                int sw = kbyte ^ ((t & 7) << 4);
                short8 bfr = *(const short8*)(cur + t * 512 + sw);
                acc[0][nf] = __builtin_amdgcn_mfma_f32_16x16x32_bf16(areg[kk][0], bfr, acc[0][nf], 0, 0, 0);
                acc[1][nf] = __builtin_amdgcn_mfma_f32_16x16x32_bf16(areg[kk][1], bfr, acc[1][nf], 0, 0, 0);
            }
        }

        // c. epilogue: reduce over a (8 tanh + 2 shuffles)
        #pragma unroll
        for (int nf = 0; nf < 4; ++nf) {
            float sv = 0.f;
            #pragma unroll
            for (int mf = 0; mf < 2; ++mf)
                #pragma unroll
                for (int r = 0; r < 4; ++r)
                    sv += wv[mf][r] * ftanh(qv[mf][r] + acc[mf][nf][r]);
            sv += __shfl_xor(sv, 16);
            sv += __shfl_xor(sv, 32);
            if (lh == 0) lpart[w * 64 + nf * 16 + lr] = sv;
        }
        lds_barrier();                            // A: lpart visible

        // d. p = exp(logit), no max-tracking (|logit| <= ~13, f32-safe)
        float lg = 0.f;
        #pragma unroll
        for (int ww = 0; ww < 8; ++ww) lg += lpart[ww * 64 + lane];
        float pself = maskL[s * 64 + lane] ? fexp(lg) : 0.f;
        if (w == 0) l_acc += pself;

        // e. PV from slab[cur]; p via in-wave shuffle
        #pragma unroll
        for (int tt = 0; tt < 4; ++tt) {
            int tl = slice4 + tt;
            float pt = __shfl(pself, tl);         // tl in [8w, 8w+8) -> same wave
            int swb = hpvb ^ ((tl & 7) << 4);
            uint4 u = *(const uint4*)(cur + tl * 512 + swb);
            a8[0] += pt * __uint_as_float(u.x << 16);
            a8[1] += pt * __uint_as_float(u.x & 0xFFFF0000u);
            a8[2] += pt * __uint_as_float(u.y << 16);
            a8[3] += pt * __uint_as_float(u.y & 0xFFFF0000u);
            a8[4] += pt * __uint_as_float(u.z << 16);
            a8[5] += pt * __uint_as_float(u.z & 0xFFFF0000u);
            a8[6] += pt * __uint_as_float(u.w << 16);
            a8[7] += pt * __uint_as_float(u.w & 0xFFFF0000u);
        }

        // f. write chunk s+1 into the idle slab (counted vmcnt lands here;
        //    loads had MFMA+epilogue+softmax+PV to arrive). PV(s) read `cur`,
        //    we write `nxt` — disjoint; next overwrite of `cur` is 2 barriers away.
        if (s + 1 < CHUNKS) { WRITE(nxt) }
    }
#undef ISSUE
#undef WRITE

    // ---- final combine: alias acc2 over slab0 (dead) ----
    __syncthreads();
    float* acc2 = (float*)smem;                   // [16][256]
    int oct = lane & 31, slice = 2 * w + (lane >> 5), h0 = oct * 8;
    *(float4*)(&acc2[slice * 256 + h0])     = (float4){a8[0], a8[1], a8[2], a8[3]};
    *(float4*)(&acc2[slice * 256 + h0 + 4]) = (float4){a8[4], a8[5], a8[6], a8[7]};
    __syncthreads();
    int pidx = g * B_DIM + b;
    if (tid < 256) {
        float ssum = 0.f;
        #pragma unroll
        for (int sl = 0; sl < 16; ++sl) ssum += acc2[sl * 256 + tid];
        part_acc[(size_t)pidx * 256 + tid] = ssum;
    }
    if (w == 0) {
        #pragma unroll
        for (int d = 1; d < 64; d <<= 1) l_acc += __shfl_xor(l_acc, d);
        if (lane == 0) part_l[pidx] = l_acc;
    }
}

// K2: fused merge (plain sums over 8 groups) + gate GEMV. block = one b.
__global__ void mergegate_kernel(const float* __restrict__ part_l,
                                 const float* __restrict__ part_acc,
                                 const float* __restrict__ input,
                                 const float* __restrict__ W_gate,
                                 float* __restrict__ gated) {
    __shared__ float ni[512];
    int b = blockIdx.x, tid = threadIdx.x;
    if (tid >= 256) {
        int k = tid - 256;
        ni[k] = input[b * 256 + k];
    } else {
        int h = tid;
        float L = 0.f, s = 0.f;
        #pragma unroll
        for (int c = 0; c < NCHG; ++c) {
            L += part_l[c * 64 + b];
            s += part_acc[(size_t)(c * 64 + b) * 256 + h];
        }
        ni[256 + h] = s / L;
    }
    __syncthreads();
    int j = tid;
    float s0 = 0.f, s1 = 0.f, s2 = 0.f, s3 = 0.f;
    #pragma unroll 4
    for (int k = 0; k < 512; k += 4) {
        s0 += ni[k]     * W_gate[(k)     * 512 + j];
        s1 += ni[k + 1] * W_gate[(k + 1) * 512 + j];
        s2 += ni[k + 2] * W_gate[(k + 2) * 512 + j];
        s3 += ni[k + 3] * W_gate[(k + 3) * 512 + j];
    }
    float s = (s0 + s1) + (s2 + s3);
    gated[b * 512 + j] = ni[j] * fsigmoid(s);
}

// K3: GRU cell. grid 256 = (16 b-tiles x 16 h-tiles), block 768.
__global__ __launch_bounds__(768) void gru_kernel(
    const float* __restrict__ gated, const float* __restrict__ state,
    const float* __restrict__ W_ih, const float* __restrict__ W_hh,
    const float* __restrict__ b_ih, const float* __restrict__ b_hh,
    float* __restrict__ out) {
    __shared__ float ld_g[4][512];
    __shared__ float ld_s[4][256];
    __shared__ float xi[3][16][4];
    __shared__ float xh[3][16][4];
    int ht = blockIdx.x & 15, bt = blockIdx.x >> 4;
    int tid = threadIdx.x;
    #pragma unroll
    for (int i = 0; i < 3; ++i) {
        int idx = i * 768 + tid;
        if (idx < 2048) ld_g[idx >> 9][idx & 511] = gated[(bt * 4 + (idx >> 9)) * 512 + (idx & 511)];
    }
    #pragma unroll
    for (int i = 0; i < 2; ++i) {
        int idx = i * 768 + tid;
        if (idx < 1024) ld_s[idx >> 8][idx & 255] = state[(bt * 4 + (idx >> 8)) * 256 + (idx & 255)];
    }

    int gid = tid >> 4, lk = tid & 15;
    int gate = gid >> 4, hl = gid & 15;
    int j = gate * 256 + ht * 16 + hl;

    float4 wi[8], wh[4];
    #pragma unroll
    for (int it = 0; it < 8; ++it)
        wi[it] = *(const float4*)(W_ih + (size_t)j * 512 + it * 64 + lk * 4);
    #pragma unroll
    for (int it = 0; it < 4; ++it)
        wh[it] = *(const float4*)(W_hh + (size_t)j * 256 + it * 64 + lk * 4);
    float bi = b_ih[j], bh = b_hh[j];
    __syncthreads();

    #pragma unroll
    for (int bb = 0; bb < 4; ++bb) {
        float g0 = 0.f, g1 = 0.f;
        #pragma unroll
        for (int it = 0; it < 8; ++it) {
            float4 gv = *(const float4*)(&ld_g[bb][it * 64 + lk * 4]);
            g0 += wi[it].x * gv.x + wi[it].z * gv.z;
            g1 += wi[it].y * gv.y + wi[it].w * gv.w;
        }
        float h0 = 0.f, h1 = 0.f;
        #pragma unroll
        for (int it = 0; it < 4; ++it) {
            float4 sv = *(const float4*)(&ld_s[bb][it * 64 + lk * 4]);
            h0 += wh[it].x * sv.x + wh[it].z * sv.z;
            h1 += wh[it].y * sv.y + wh[it].w * sv.w;
        }
        float gi_ = g0 + g1, gh_ = h0 + h1;
        #pragma unroll
        for (int m = 1; m < 16; m <<= 1) {
            gi_ += __shfl_xor(gi_, m);
            gh_ += __shfl_xor(gh_, m);
        }
        if (lk == 0) { xi[gate][hl][bb] = gi_ + bi; xh[gate][hl][bb] = gh_ + bh; }
    }
    __syncthreads();
    if (tid < 64) {
        int bb = tid >> 4, hl2 = tid & 15;
        float ir = xi[0][hl2][bb], hr = xh[0][hl2][bb];
        float iz = xi[1][hl2][bb], hz = xh[1][hl2][bb];
        float in_ = xi[2][hl2][bb], hn = xh[2][hl2][bb];
        float r = fsigmoid(ir + hr);
        float z = fsigmoid(iz + hz);
        float n = ftanh(in_ + r * hn);
        out[(bt * 4 + bb) * 256 + ht * 16 + hl2] =
            (1.f - z) * n + z * ld_s[bb][ht * 16 + hl2];
    }
}

extern "C" void kernel_launch(void* const* d_in, const int* in_sizes, int n_in,
                              void* d_out, int out_size, void* d_ws, size_t ws_size,
                              hipStream_t stream) {
    const float* input  = (const float*)d_in[0];
    const float* memory = (const float*)d_in[1];
    const int*   mask   = (const int*)d_in[2];
    const float* state  = (const float*)d_in[3];
    const float* W_a1   = (const float*)d_in[4];
    const float* w_a2   = (const float*)d_in[5];
    const float* W_gate = (const float*)d_in[6];
    const float* W_ih   = (const float*)d_in[7];
    const float* W_hh   = (const float*)d_in[8];
    const float* b_ih   = (const float*)d_in[9];
    const float* b_hh   = (const float*)d_in[10];
    float* out = (float*)d_out;

    char* ws = (char*)d_ws;
    unsigned short* WmT = (unsigned short*)(ws + 0);        // 131072 B
    float* qs       = (float*)(ws + 131072);                // 65536 B
    float* gated    = (float*)(ws + 196608);                // 131072 B
    float* part_l   = (float*)(ws + 327680);                // 2048 B   [g][b]
    float* part_acc = (float*)(ws + 335872);                // 524288 B [g][b][h]

    prep_qs_kernel<<<320, 256, 0, stream>>>(W_a1, input, state, WmT, qs);

    (void)hipFuncSetAttribute((const void*)attn_kernel,
                              hipFuncAttributeMaxDynamicSharedMemorySize, 68608);
    attn_kernel<<<dim3(B_DIM, NCHG), 512, 68608, stream>>>(
        memory, mask, WmT, qs, w_a2, part_l, part_acc);

    mergegate_kernel<<<64, 512, 0, stream>>>(part_l, part_acc, input, W_gate, gated);
    gru_kernel<<<256, 768, 0, stream>>>(gated, state, W_ih, W_hh, b_ih, b_hh, out);
}